// Round 1
// baseline (382.911 us; speedup 1.0000x reference)
//
#include <hip/hip_runtime.h>
#include <hip/hip_bf16.h>

// WindowAttention3D: B_=3136 windows, N=64 tokens, C=128, H=4 heads, hd=32.
// One block per window, 256 threads = 4 waves. bf16 MFMA (16x16x32) everywhere.

typedef __bf16 bf16x8 __attribute__((ext_vector_type(8)));
typedef __bf16 bf16x4 __attribute__((ext_vector_type(4)));
typedef float f32x4 __attribute__((ext_vector_type(4)));

#define NWMASK 392
#define SCALE 0.17677669529663687f  // 1/sqrt(32)

// ---------------- pre-kernels ----------------
__global__ void prep_weights(const float* __restrict__ qkv_w,
                             const float* __restrict__ proj_w,
                             __bf16* __restrict__ wqkv,
                             __bf16* __restrict__ wproj) {
    int i = blockIdx.x * 256 + threadIdx.x;      // 65536 threads total
    if (i < 49152) {
        wqkv[i] = (__bf16)qkv_w[i];              // [384][128]
    } else {
        int j = i - 49152;                       // [128][128]
        wproj[j] = (__bf16)proj_w[j];
    }
}

__global__ void prep_rpe(const float* __restrict__ tbl,
                         const int* __restrict__ ridx,
                         float* __restrict__ rpe) {
    int i = blockIdx.x * 256 + threadIdx.x;      // 16384 = 4*64*64
    int h = i >> 12;
    int nm = i & 4095;
    rpe[i] = tbl[ridx[nm] * 4 + h];
}

// ---------------- main fused kernel ----------------
// LDS layout (bytes), 59392 total:
//   [0,20480)     qs  [h][64][40] bf16   (q, pre-scaled)
//   [20480,40960) ks  [h][64][40] bf16
//   [40960,59392) vt  [h][32][72] bf16   (V transposed: [dim][token])
// overlays on [0,40960):
//   ps  [h][64][72] bf16 (36864 B)  -- softmax P, C-layout -> A-layout round-trip
//   os  [64][136]   bf16 (17408 B)  -- attention output, pre-proj
__global__ __launch_bounds__(256, 2) void wattn_main(
    const float* __restrict__ x, const float* __restrict__ mask,
    const float* __restrict__ qkv_b, const float* __restrict__ proj_b,
    const __bf16* __restrict__ wqkv, const __bf16* __restrict__ wproj,
    const float* __restrict__ rpe, float* __restrict__ out)
{
    __shared__ __align__(16) unsigned char smem_raw[59392];
    __bf16* const qs = (__bf16*)smem_raw;
    __bf16* const ks = (__bf16*)(smem_raw + 20480);
    __bf16* const vt = (__bf16*)(smem_raw + 40960);
    __bf16* const ps = (__bf16*)smem_raw;
    __bf16* const os = (__bf16*)smem_raw;

    const int win  = blockIdx.x;
    const int tid  = threadIdx.x;
    const int wv   = tid >> 6;       // wave id = token band (phase 2/5), head (phase 3/4)
    const int lane = tid & 63;
    const int quad = lane >> 4;
    const int l16  = lane & 15;
    const int trow = wv * 16 + quad * 4;   // C-layout base row for this wave

    // ---- Phase 1: load x A-fragments (rows wv*16+l16), fp32 -> bf16, regs only ----
    bf16x8 af[4];
    {
        const float* xp = x + ((size_t)win * 64 + wv * 16 + l16) * 128 + quad * 8;
        #pragma unroll
        for (int kt = 0; kt < 4; ++kt) {
            float4 a0 = *(const float4*)(xp + kt * 32);
            float4 a1 = *(const float4*)(xp + kt * 32 + 4);
            bf16x8 t;
            t[0] = (__bf16)a0.x; t[1] = (__bf16)a0.y; t[2] = (__bf16)a0.z; t[3] = (__bf16)a0.w;
            t[4] = (__bf16)a1.x; t[5] = (__bf16)a1.y; t[6] = (__bf16)a1.z; t[7] = (__bf16)a1.w;
            af[kt] = t;
        }
    }

    // ---- Phase 2: QKV GEMM (M=64 band per wave, N=384, K=128) ----
    // Q: features [0,128) -> qs, scaled
    #pragma unroll
    for (int nt = 0; nt < 8; ++nt) {
        const int ng = nt * 16 + l16;
        f32x4 acc = {0.f, 0.f, 0.f, 0.f};
        const __bf16* wb = wqkv + ng * 128 + quad * 8;
        #pragma unroll
        for (int kt = 0; kt < 4; ++kt)
            acc = __builtin_amdgcn_mfma_f32_16x16x32_bf16(af[kt], *(const bf16x8*)(wb + kt * 32), acc, 0, 0, 0);
        const float b = qkv_b[ng];
        __bf16* dst = qs + (nt >> 1) * 2560 + trow * 40 + (nt & 1) * 16 + l16;
        #pragma unroll
        for (int r = 0; r < 4; ++r) dst[r * 40] = (__bf16)((acc[r] + b) * SCALE);
    }
    // K: features [128,256) -> ks
    #pragma unroll
    for (int nt = 0; nt < 8; ++nt) {
        const int ng = 128 + nt * 16 + l16;
        f32x4 acc = {0.f, 0.f, 0.f, 0.f};
        const __bf16* wb = wqkv + ng * 128 + quad * 8;
        #pragma unroll
        for (int kt = 0; kt < 4; ++kt)
            acc = __builtin_amdgcn_mfma_f32_16x16x32_bf16(af[kt], *(const bf16x8*)(wb + kt * 32), acc, 0, 0, 0);
        const float b = qkv_b[ng];
        __bf16* dst = ks + (nt >> 1) * 2560 + trow * 40 + (nt & 1) * 16 + l16;
        #pragma unroll
        for (int r = 0; r < 4; ++r) dst[r * 40] = (__bf16)(acc[r] + b);
    }
    // V: features [256,384) -> vt transposed [dim][token]
    #pragma unroll
    for (int nt = 0; nt < 8; ++nt) {
        const int ng = 256 + nt * 16 + l16;
        f32x4 acc = {0.f, 0.f, 0.f, 0.f};
        const __bf16* wb = wqkv + ng * 128 + quad * 8;
        #pragma unroll
        for (int kt = 0; kt < 4; ++kt)
            acc = __builtin_amdgcn_mfma_f32_16x16x32_bf16(af[kt], *(const bf16x8*)(wb + kt * 32), acc, 0, 0, 0);
        const float b = qkv_b[ng];
        bf16x4 pk;
        #pragma unroll
        for (int r = 0; r < 4; ++r) pk[r] = (__bf16)(acc[r] + b);
        *(bf16x4*)(vt + (nt >> 1) * 2304 + ((nt & 1) * 16 + l16) * 72 + trow) = pk;
    }
    __syncthreads();   // qs/ks/vt complete

    // ---- Phase 3: per-head attention scores + softmax (wave wv = head h) ----
    const int h = wv;
    bf16x8 qf[4], kf[4];
    #pragma unroll
    for (int t = 0; t < 4; ++t) {
        qf[t] = *(const bf16x8*)(qs + h * 2560 + (t * 16 + l16) * 40 + quad * 8);
        kf[t] = *(const bf16x8*)(ks + h * 2560 + (t * 16 + l16) * 40 + quad * 8);
    }
    f32x4 sc[4][4];
    #pragma unroll
    for (int mt = 0; mt < 4; ++mt)
        #pragma unroll
        for (int nt = 0; nt < 4; ++nt) {
            f32x4 z = {0.f, 0.f, 0.f, 0.f};
            sc[mt][nt] = __builtin_amdgcn_mfma_f32_16x16x32_bf16(qf[mt], kf[nt], z, 0, 0, 0);
        }

    const float* rpeh = rpe + h * 4096;
    const float* mw   = mask + (size_t)(win % NWMASK) * 4096;
    float inv_s[4][4];
    #pragma unroll
    for (int mt = 0; mt < 4; ++mt) {
        #pragma unroll
        for (int r = 0; r < 4; ++r) {
            const int row = mt * 16 + quad * 4 + r;
            float mx = -3.0e38f;
            #pragma unroll
            for (int nt = 0; nt < 4; ++nt) {
                const int col = nt * 16 + l16;
                float lg = sc[mt][nt][r] + rpeh[row * 64 + col] + mw[row * 64 + col];
                sc[mt][nt][r] = lg;
                mx = fmaxf(mx, lg);
            }
            #pragma unroll
            for (int s = 1; s < 16; s <<= 1) mx = fmaxf(mx, __shfl_xor(mx, s, 64));
            float sum = 0.f;
            #pragma unroll
            for (int nt = 0; nt < 4; ++nt) {
                float e = __expf(sc[mt][nt][r] - mx);
                sc[mt][nt][r] = e;
                sum += e;
            }
            #pragma unroll
            for (int s = 1; s < 16; s <<= 1) sum += __shfl_xor(sum, s, 64);
            inv_s[mt][r] = 1.0f / sum;
        }
    }
    __syncthreads();   // all waves done reading qs/ks -> safe to overlay ps

    __bf16* const psh = ps + h * 4608;
    #pragma unroll
    for (int mt = 0; mt < 4; ++mt)
        #pragma unroll
        for (int nt = 0; nt < 4; ++nt)
            #pragma unroll
            for (int r = 0; r < 4; ++r)
                psh[(mt * 16 + quad * 4 + r) * 72 + nt * 16 + l16] = (__bf16)sc[mt][nt][r];
    __syncthreads();   // ps ready

    // ---- Phase 4: O = P @ V (per head), rows scaled by 1/sum ----
    bf16x8 vf[2][2];
    #pragma unroll
    for (int kt = 0; kt < 2; ++kt)
        #pragma unroll
        for (int nt = 0; nt < 2; ++nt)
            vf[kt][nt] = *(const bf16x8*)(vt + h * 2304 + (nt * 16 + l16) * 72 + kt * 32 + quad * 8);
    f32x4 oa[4][2];
    #pragma unroll
    for (int mt = 0; mt < 4; ++mt) {
        oa[mt][0] = (f32x4){0.f, 0.f, 0.f, 0.f};
        oa[mt][1] = (f32x4){0.f, 0.f, 0.f, 0.f};
        #pragma unroll
        for (int kt = 0; kt < 2; ++kt) {
            bf16x8 pf = *(const bf16x8*)(psh + (mt * 16 + l16) * 72 + kt * 32 + quad * 8);
            #pragma unroll
            for (int nt = 0; nt < 2; ++nt)
                oa[mt][nt] = __builtin_amdgcn_mfma_f32_16x16x32_bf16(pf, vf[kt][nt], oa[mt][nt], 0, 0, 0);
        }
    }
    __syncthreads();   // all waves done reading ps -> safe to overlay os

    #pragma unroll
    for (int mt = 0; mt < 4; ++mt)
        #pragma unroll
        for (int nt = 0; nt < 2; ++nt)
            #pragma unroll
            for (int r = 0; r < 4; ++r)
                os[(mt * 16 + quad * 4 + r) * 136 + h * 32 + nt * 16 + l16] =
                    (__bf16)(oa[mt][nt][r] * inv_s[mt][r]);
    __syncthreads();   // os ready

    // ---- Phase 5: proj GEMM (M=64 band per wave, N=128, K=128) + bias, fp32 out ----
    bf16x8 of[4];
    #pragma unroll
    for (int kt = 0; kt < 4; ++kt)
        of[kt] = *(const bf16x8*)(os + (wv * 16 + l16) * 136 + kt * 32 + quad * 8);
    #pragma unroll
    for (int nt = 0; nt < 8; ++nt) {
        const int ng = nt * 16 + l16;
        f32x4 acc = {0.f, 0.f, 0.f, 0.f};
        const __bf16* wb = wproj + ng * 128 + quad * 8;
        #pragma unroll
        for (int kt = 0; kt < 4; ++kt)
            acc = __builtin_amdgcn_mfma_f32_16x16x32_bf16(of[kt], *(const bf16x8*)(wb + kt * 32), acc, 0, 0, 0);
        const float b = proj_b[ng];
        float* dst = out + ((size_t)win * 64 + trow) * 128 + ng;
        #pragma unroll
        for (int r = 0; r < 4; ++r) dst[(size_t)r * 128] = acc[r] + b;
    }
}

// ---------------- launch ----------------
extern "C" void kernel_launch(void* const* d_in, const int* in_sizes, int n_in,
                              void* d_out, int out_size, void* d_ws, size_t ws_size,
                              hipStream_t stream) {
    const float* x      = (const float*)d_in[0];
    const float* mask   = (const float*)d_in[1];
    const float* qkv_w  = (const float*)d_in[2];
    const float* qkv_b  = (const float*)d_in[3];
    const float* proj_w = (const float*)d_in[4];
    const float* proj_b = (const float*)d_in[5];
    const float* tbl    = (const float*)d_in[6];
    const int*   ridx   = (const int*)d_in[7];
    float* out = (float*)d_out;

    // workspace layout: wqkv bf16 [384*128] | wproj bf16 [128*128] | rpe f32 [4*64*64]
    __bf16* wqkv  = (__bf16*)d_ws;
    __bf16* wproj = wqkv + 384 * 128;
    float*  rpe   = (float*)((char*)d_ws + 131072);

    prep_weights<<<256, 256, 0, stream>>>(qkv_w, proj_w, wqkv, wproj);
    prep_rpe<<<64, 256, 0, stream>>>(tbl, ridx, rpe);
    wattn_main<<<3136, 256, 0, stream>>>(x, mask, qkv_b, proj_b, wqkv, wproj, rpe, out);
}

// Round 2
// 353.607 us; speedup vs baseline: 1.0829x; 1.0829x over previous
//
#include <hip/hip_runtime.h>
#include <hip/hip_bf16.h>

// WindowAttention3D: 3136 windows, N=64 tokens, C=128, H=4 heads, hd=32.
// One block per window, 4 waves, wave = head end-to-end. All inter-phase data
// moves through WAVE-PRIVATE LDS (in-order DS ops, no barrier); single
// __syncthreads() before the proj GEMM (cross-head K-reduction).
// LDS/block = 38912 B -> 4 blocks/CU; __launch_bounds__(256,4) caps VGPR at 128.

typedef __bf16 bf16x8 __attribute__((ext_vector_type(8)));
typedef __bf16 bf16x4 __attribute__((ext_vector_type(4)));
typedef float f32x4 __attribute__((ext_vector_type(4)));

#define NWMASK 392
#define SCALE 0.17677669529663687f  // 1/sqrt(32)

// ---------------- prep: weights->bf16, rpe gather (single kernel) ----------------
__global__ void prep(const float* __restrict__ qkv_w, const float* __restrict__ proj_w,
                     const float* __restrict__ tbl, const int* __restrict__ ridx,
                     __bf16* __restrict__ wqkv, __bf16* __restrict__ wproj,
                     float* __restrict__ rpe) {
    int i = blockIdx.x * 256 + threadIdx.x;          // 81920 threads
    if (i < 49152) {
        wqkv[i] = (__bf16)qkv_w[i];                  // [384][128]
    } else if (i < 65536) {
        int j = i - 49152;  wproj[j] = (__bf16)proj_w[j];   // [128][128]
    } else {
        int j = i - 65536;                           // rpe [4][64][64]
        rpe[j] = tbl[ridx[j & 4095] * 4 + (j >> 12)];
    }
}

// ---------------- main fused kernel ----------------
// Per-wave LDS region (4864 bf16 = 9728 B):
//   buf [64][40] bf16 (2560 el): K staging -> Q staging -> O_head (os_h)
//   vt  [32][72] bf16 (2304 el): V^T -> P bands (16x72 per mt)
__global__ __launch_bounds__(256, 4) void wattn_main(
    const float* __restrict__ x, const float* __restrict__ mask,
    const float* __restrict__ qkv_b, const float* __restrict__ proj_b,
    const __bf16* __restrict__ wqkv, const __bf16* __restrict__ wproj,
    const float* __restrict__ rpe, float* __restrict__ out)
{
    __shared__ __align__(16) __bf16 smem[4 * 4864];   // 38912 B
    const int win  = blockIdx.x;
    const int tid  = threadIdx.x;
    const int h    = tid >> 6;        // wave id = head (and token band in proj)
    const int lane = tid & 63;
    const int quad = lane >> 4;
    const int l16  = lane & 15;

    __bf16* const buf = smem + h * 4864;
    __bf16* const vt  = buf + 2560;

    // ---- x A-fragments for all 4 row-bands, fp32 -> bf16, registers (64 VGPR) ----
    bf16x8 af[4][4];
    {
        const float* xb = x + ((size_t)win * 64 + l16) * 128 + quad * 8;
        #pragma unroll
        for (int mt = 0; mt < 4; ++mt) {
            const float* xp = xb + mt * 16 * 128;
            #pragma unroll
            for (int kt = 0; kt < 4; ++kt) {
                float4 a0 = *(const float4*)(xp + kt * 32);
                float4 a1 = *(const float4*)(xp + kt * 32 + 4);
                bf16x8 t;
                t[0] = (__bf16)a0.x; t[1] = (__bf16)a0.y; t[2] = (__bf16)a0.z; t[3] = (__bf16)a0.w;
                t[4] = (__bf16)a1.x; t[5] = (__bf16)a1.y; t[6] = (__bf16)a1.z; t[7] = (__bf16)a1.w;
                af[mt][kt] = t;
            }
        }
    }

    bf16x8 kf[4], qf[4], vf[2][2];

    // ---- K for head h (features 128+h*32+[0,32)) -> buf -> kf (B-frags) ----
    #pragma unroll
    for (int nt = 0; nt < 2; ++nt) {
        const int ng = 128 + h * 32 + nt * 16 + l16;
        const float b = qkv_b[ng];
        bf16x8 wf[4];
        #pragma unroll
        for (int kt = 0; kt < 4; ++kt) wf[kt] = *(const bf16x8*)(wqkv + ng * 128 + kt * 32 + quad * 8);
        #pragma unroll
        for (int mt = 0; mt < 4; ++mt) {
            f32x4 acc = {0.f, 0.f, 0.f, 0.f};
            #pragma unroll
            for (int kt = 0; kt < 4; ++kt)
                acc = __builtin_amdgcn_mfma_f32_16x16x32_bf16(af[mt][kt], wf[kt], acc, 0, 0, 0);
            #pragma unroll
            for (int r = 0; r < 4; ++r)
                buf[(mt * 16 + quad * 4 + r) * 40 + nt * 16 + l16] = (__bf16)(acc[r] + b);
        }
    }
    #pragma unroll
    for (int nt = 0; nt < 4; ++nt) kf[nt] = *(const bf16x8*)(buf + (nt * 16 + l16) * 40 + quad * 8);

    // ---- V for head h (features 256+h*32+[0,32)) -> vt transposed [feat][token] ----
    #pragma unroll
    for (int nt = 0; nt < 2; ++nt) {
        const int ng = 256 + h * 32 + nt * 16 + l16;
        const float b = qkv_b[ng];
        bf16x8 wf[4];
        #pragma unroll
        for (int kt = 0; kt < 4; ++kt) wf[kt] = *(const bf16x8*)(wqkv + ng * 128 + kt * 32 + quad * 8);
        #pragma unroll
        for (int mt = 0; mt < 4; ++mt) {
            f32x4 acc = {0.f, 0.f, 0.f, 0.f};
            #pragma unroll
            for (int kt = 0; kt < 4; ++kt)
                acc = __builtin_amdgcn_mfma_f32_16x16x32_bf16(af[mt][kt], wf[kt], acc, 0, 0, 0);
            bf16x4 pk;
            #pragma unroll
            for (int r = 0; r < 4; ++r) pk[r] = (__bf16)(acc[r] + b);
            *(bf16x4*)(vt + (nt * 16 + l16) * 72 + mt * 16 + quad * 4) = pk;
        }
    }

    // ---- Q for head h (features h*32+[0,32), pre-scaled) -> buf -> qf (A-frags) ----
    #pragma unroll
    for (int nt = 0; nt < 2; ++nt) {
        const int ng = h * 32 + nt * 16 + l16;
        const float b = qkv_b[ng];
        bf16x8 wf[4];
        #pragma unroll
        for (int kt = 0; kt < 4; ++kt) wf[kt] = *(const bf16x8*)(wqkv + ng * 128 + kt * 32 + quad * 8);
        #pragma unroll
        for (int mt = 0; mt < 4; ++mt) {
            f32x4 acc = {0.f, 0.f, 0.f, 0.f};
            #pragma unroll
            for (int kt = 0; kt < 4; ++kt)
                acc = __builtin_amdgcn_mfma_f32_16x16x32_bf16(af[mt][kt], wf[kt], acc, 0, 0, 0);
            #pragma unroll
            for (int r = 0; r < 4; ++r)
                buf[(mt * 16 + quad * 4 + r) * 40 + nt * 16 + l16] = (__bf16)((acc[r] + b) * SCALE);
        }
    }
    #pragma unroll
    for (int mt = 0; mt < 4; ++mt) qf[mt] = *(const bf16x8*)(buf + (mt * 16 + l16) * 40 + quad * 8);

    // ---- V B-frags (vt then becomes P-band scratch) ----
    #pragma unroll
    for (int kt = 0; kt < 2; ++kt)
        #pragma unroll
        for (int nf = 0; nf < 2; ++nf)
            vf[kt][nf] = *(const bf16x8*)(vt + (nf * 16 + l16) * 72 + kt * 32 + quad * 8);

    // ---- attention per 16-row band: S -> softmax -> P band -> P@V -> os_h (buf) ----
    const float* rpeh = rpe + h * 4096;
    const float* mw   = mask + (size_t)(win % NWMASK) * 4096;
    #pragma unroll
    for (int mt = 0; mt < 4; ++mt) {
        f32x4 sc[4];
        #pragma unroll
        for (int nt = 0; nt < 4; ++nt) {
            f32x4 z = {0.f, 0.f, 0.f, 0.f};
            sc[nt] = __builtin_amdgcn_mfma_f32_16x16x32_bf16(qf[mt], kf[nt], z, 0, 0, 0);
        }
        float inv_s[4];
        #pragma unroll
        for (int r = 0; r < 4; ++r) {
            const int row = mt * 16 + quad * 4 + r;
            float mx = -3.0e38f;
            #pragma unroll
            for (int nt = 0; nt < 4; ++nt) {
                float lg = sc[nt][r] + rpeh[row * 64 + nt * 16 + l16] + mw[row * 64 + nt * 16 + l16];
                sc[nt][r] = lg;
                mx = fmaxf(mx, lg);
            }
            #pragma unroll
            for (int s = 1; s < 16; s <<= 1) mx = fmaxf(mx, __shfl_xor(mx, s, 64));
            float sum = 0.f;
            #pragma unroll
            for (int nt = 0; nt < 4; ++nt) {
                float e = __expf(sc[nt][r] - mx);
                sc[nt][r] = e;
                sum += e;
            }
            #pragma unroll
            for (int s = 1; s < 16; s <<= 1) sum += __shfl_xor(sum, s, 64);
            inv_s[r] = 1.0f / sum;
        }
        // P band (16x64) -> vt scratch (C-layout -> A-layout round trip, wave-private)
        #pragma unroll
        for (int nt = 0; nt < 4; ++nt)
            #pragma unroll
            for (int r = 0; r < 4; ++r)
                vt[(quad * 4 + r) * 72 + nt * 16 + l16] = (__bf16)sc[nt][r];
        f32x4 oa[2] = {{0.f,0.f,0.f,0.f},{0.f,0.f,0.f,0.f}};
        #pragma unroll
        for (int kt = 0; kt < 2; ++kt) {
            bf16x8 pf = *(const bf16x8*)(vt + l16 * 72 + kt * 32 + quad * 8);
            #pragma unroll
            for (int nf = 0; nf < 2; ++nf)
                oa[nf] = __builtin_amdgcn_mfma_f32_16x16x32_bf16(pf, vf[kt][nf], oa[nf], 0, 0, 0);
        }
        #pragma unroll
        for (int nf = 0; nf < 2; ++nf)
            #pragma unroll
            for (int r = 0; r < 4; ++r)
                buf[(mt * 16 + quad * 4 + r) * 40 + nf * 16 + l16] = (__bf16)(oa[nf][r] * inv_s[r]);
    }

    __syncthreads();   // the ONLY barrier: os_h (per-wave bufs) -> all waves

    // ---- proj GEMM: wave h = token band h*16..h*16+15, K=128 across 4 heads ----
    bf16x8 of[4];
    #pragma unroll
    for (int kt = 0; kt < 4; ++kt)
        of[kt] = *(const bf16x8*)(smem + kt * 4864 + (h * 16 + l16) * 40 + quad * 8);
    #pragma unroll
    for (int nt = 0; nt < 8; ++nt) {
        const int ng = nt * 16 + l16;
        const float b = proj_b[ng];
        bf16x8 wf[4];
        #pragma unroll
        for (int kt = 0; kt < 4; ++kt) wf[kt] = *(const bf16x8*)(wproj + ng * 128 + kt * 32 + quad * 8);
        f32x4 acc = {0.f, 0.f, 0.f, 0.f};
        #pragma unroll
        for (int kt = 0; kt < 4; ++kt)
            acc = __builtin_amdgcn_mfma_f32_16x16x32_bf16(of[kt], wf[kt], acc, 0, 0, 0);
        float* dst = out + ((size_t)win * 64 + h * 16 + quad * 4) * 128 + ng;
        #pragma unroll
        for (int r = 0; r < 4; ++r) dst[(size_t)r * 128] = acc[r] + b;
    }
}

// ---------------- launch ----------------
extern "C" void kernel_launch(void* const* d_in, const int* in_sizes, int n_in,
                              void* d_out, int out_size, void* d_ws, size_t ws_size,
                              hipStream_t stream) {
    const float* x      = (const float*)d_in[0];
    const float* mask   = (const float*)d_in[1];
    const float* qkv_w  = (const float*)d_in[2];
    const float* qkv_b  = (const float*)d_in[3];
    const float* proj_w = (const float*)d_in[4];
    const float* proj_b = (const float*)d_in[5];
    const float* tbl    = (const float*)d_in[6];
    const int*   ridx   = (const int*)d_in[7];
    float* out = (float*)d_out;

    // ws: wqkv bf16 [384*128] | wproj bf16 [128*128] | rpe f32 [4*64*64]
    __bf16* wqkv  = (__bf16*)d_ws;
    __bf16* wproj = wqkv + 384 * 128;
    float*  rpe   = (float*)((char*)d_ws + 131072);

    prep<<<320, 256, 0, stream>>>(qkv_w, proj_w, tbl, ridx, wqkv, wproj, rpe);
    wattn_main<<<3136, 256, 0, stream>>>(x, mask, qkv_b, proj_b, wqkv, wproj, rpe, out);
}

// Round 3
// 275.675 us; speedup vs baseline: 1.3890x; 1.2827x over previous
//
#include <hip/hip_runtime.h>
#include <hip/hip_bf16.h>

// WindowAttention3D: 3136 windows, N=64 tokens, C=128, H=4 heads, hd=32.
// One block per window, 4 waves, wave = head. x is staged ONCE in LDS (bf16)
// and all phases read A-fragments from LDS -> register demand ~110, no spills.
// LDS 37,888 B -> 4 blocks/CU. 3 barriers total.
//
// LDS map (bf16 elements):
//   [0, 8704)        xs  [64][136]  x staging   -- overlay: os 4 x [64][34] (O staging)
//   [8704, 18944)    per-wave buf 2560 el: K stage -> Q stage -> V^T [32][72] -> P [16][72]

typedef __bf16 bf16x8 __attribute__((ext_vector_type(8)));
typedef __bf16 bf16x4 __attribute__((ext_vector_type(4)));
typedef float f32x4 __attribute__((ext_vector_type(4)));

#define NWMASK 392
#define SCALE 0.17677669529663687f  // 1/sqrt(32)

// ---------------- prep: weights->bf16, rpe gather ----------------
__global__ void prep(const float* __restrict__ qkv_w, const float* __restrict__ proj_w,
                     const float* __restrict__ tbl, const int* __restrict__ ridx,
                     __bf16* __restrict__ wqkv, __bf16* __restrict__ wproj,
                     float* __restrict__ rpe) {
    int i = blockIdx.x * 256 + threadIdx.x;          // 81920 threads
    if (i < 49152) {
        wqkv[i] = (__bf16)qkv_w[i];                  // [384][128]
    } else if (i < 65536) {
        int j = i - 49152;  wproj[j] = (__bf16)proj_w[j];   // [128][128]
    } else {
        int j = i - 65536;                           // rpe [4][64][64]
        rpe[j] = tbl[ridx[j & 4095] * 4 + (j >> 12)];
    }
}

// ---------------- main fused kernel ----------------
__global__ __launch_bounds__(256, 4) void wattn_main(
    const float* __restrict__ x, const float* __restrict__ mask,
    const float* __restrict__ qkv_b, const float* __restrict__ proj_b,
    const __bf16* __restrict__ wqkv, const __bf16* __restrict__ wproj,
    const float* __restrict__ rpe, float* __restrict__ out)
{
    __shared__ __align__(16) __bf16 smem[18944];   // 37888 B
    const int win  = blockIdx.x;
    const int tid  = threadIdx.x;
    const int h    = tid >> 6;        // wave id = head (and token band in phase0/proj)
    const int lane = tid & 63;
    const int quad = lane >> 4;
    const int l16  = lane & 15;

    __bf16* const xs  = smem;                     // [64][136]
    __bf16* const buf = smem + 8704 + h * 2560;   // wave-private
    __bf16* const osw = smem + h * 2176;          // O staging [64][34], overlays xs

    // ---- Phase 0: cooperative x staging, fp32 -> bf16, fully coalesced ----
    {
        const float* xb = x + (size_t)win * 8192;
        #pragma unroll
        for (int i = 0; i < 2; ++i) {
            const int row  = h * 16 + (lane >> 3) + i * 8;
            const int colg = (lane & 7) * 16;
            const float* xp = xb + row * 128 + colg;
            float4 a0 = *(const float4*)(xp);
            float4 a1 = *(const float4*)(xp + 4);
            float4 a2 = *(const float4*)(xp + 8);
            float4 a3 = *(const float4*)(xp + 12);
            bf16x8 t0, t1;
            t0[0]=(__bf16)a0.x; t0[1]=(__bf16)a0.y; t0[2]=(__bf16)a0.z; t0[3]=(__bf16)a0.w;
            t0[4]=(__bf16)a1.x; t0[5]=(__bf16)a1.y; t0[6]=(__bf16)a1.z; t0[7]=(__bf16)a1.w;
            t1[0]=(__bf16)a2.x; t1[1]=(__bf16)a2.y; t1[2]=(__bf16)a2.z; t1[3]=(__bf16)a2.w;
            t1[4]=(__bf16)a3.x; t1[5]=(__bf16)a3.y; t1[6]=(__bf16)a3.z; t1[7]=(__bf16)a3.w;
            *(bf16x8*)(xs + row * 136 + colg)     = t0;
            *(bf16x8*)(xs + row * 136 + colg + 8) = t1;
        }
    }
    __syncthreads();   // barrier 1: xs ready

    bf16x8 kf[4], qf[4], vf[2][2];

    // ---- K phase: feats 128+h*32+[0,32) -> buf [64][40] -> kf (B-frags) ----
    {
        bf16x8 wf[2][4]; float bb[2];
        #pragma unroll
        for (int nt = 0; nt < 2; ++nt) {
            const int ng = 128 + h * 32 + nt * 16 + l16;
            bb[nt] = qkv_b[ng];
            #pragma unroll
            for (int kt = 0; kt < 4; ++kt)
                wf[nt][kt] = *(const bf16x8*)(wqkv + ng * 128 + kt * 32 + quad * 8);
        }
        #pragma unroll
        for (int mt = 0; mt < 4; ++mt) {
            bf16x8 af[4];
            #pragma unroll
            for (int kt = 0; kt < 4; ++kt)
                af[kt] = *(const bf16x8*)(xs + (mt * 16 + l16) * 136 + kt * 32 + quad * 8);
            #pragma unroll
            for (int nt = 0; nt < 2; ++nt) {
                f32x4 acc = {0.f, 0.f, 0.f, 0.f};
                #pragma unroll
                for (int kt = 0; kt < 4; ++kt)
                    acc = __builtin_amdgcn_mfma_f32_16x16x32_bf16(af[kt], wf[nt][kt], acc, 0, 0, 0);
                #pragma unroll
                for (int r = 0; r < 4; ++r)
                    buf[(mt * 16 + quad * 4 + r) * 40 + nt * 16 + l16] = (__bf16)(acc[r] + bb[nt]);
            }
        }
        #pragma unroll
        for (int j = 0; j < 4; ++j)
            kf[j] = *(const bf16x8*)(buf + (j * 16 + l16) * 40 + quad * 8);
    }

    // ---- Q phase: feats h*32+[0,32), pre-scaled -> buf -> qf (A-frags) ----
    {
        bf16x8 wf[2][4]; float bb[2];
        #pragma unroll
        for (int nt = 0; nt < 2; ++nt) {
            const int ng = h * 32 + nt * 16 + l16;
            bb[nt] = qkv_b[ng];
            #pragma unroll
            for (int kt = 0; kt < 4; ++kt)
                wf[nt][kt] = *(const bf16x8*)(wqkv + ng * 128 + kt * 32 + quad * 8);
        }
        #pragma unroll
        for (int mt = 0; mt < 4; ++mt) {
            bf16x8 af[4];
            #pragma unroll
            for (int kt = 0; kt < 4; ++kt)
                af[kt] = *(const bf16x8*)(xs + (mt * 16 + l16) * 136 + kt * 32 + quad * 8);
            #pragma unroll
            for (int nt = 0; nt < 2; ++nt) {
                f32x4 acc = {0.f, 0.f, 0.f, 0.f};
                #pragma unroll
                for (int kt = 0; kt < 4; ++kt)
                    acc = __builtin_amdgcn_mfma_f32_16x16x32_bf16(af[kt], wf[nt][kt], acc, 0, 0, 0);
                #pragma unroll
                for (int r = 0; r < 4; ++r)
                    buf[(mt * 16 + quad * 4 + r) * 40 + nt * 16 + l16] = (__bf16)((acc[r] + bb[nt]) * SCALE);
            }
        }
        #pragma unroll
        for (int mt = 0; mt < 4; ++mt)
            qf[mt] = *(const bf16x8*)(buf + (mt * 16 + l16) * 40 + quad * 8);
    }

    // ---- V phase: feats 256+h*32+[0,32) -> buf as V^T [32 feat][72 tok] -> vf ----
    {
        bf16x8 wf[2][4]; float bb[2];
        #pragma unroll
        for (int nt = 0; nt < 2; ++nt) {
            const int ng = 256 + h * 32 + nt * 16 + l16;
            bb[nt] = qkv_b[ng];
            #pragma unroll
            for (int kt = 0; kt < 4; ++kt)
                wf[nt][kt] = *(const bf16x8*)(wqkv + ng * 128 + kt * 32 + quad * 8);
        }
        #pragma unroll
        for (int mt = 0; mt < 4; ++mt) {
            bf16x8 af[4];
            #pragma unroll
            for (int kt = 0; kt < 4; ++kt)
                af[kt] = *(const bf16x8*)(xs + (mt * 16 + l16) * 136 + kt * 32 + quad * 8);
            #pragma unroll
            for (int nt = 0; nt < 2; ++nt) {
                f32x4 acc = {0.f, 0.f, 0.f, 0.f};
                #pragma unroll
                for (int kt = 0; kt < 4; ++kt)
                    acc = __builtin_amdgcn_mfma_f32_16x16x32_bf16(af[kt], wf[nt][kt], acc, 0, 0, 0);
                bf16x4 pk;
                #pragma unroll
                for (int r = 0; r < 4; ++r) pk[r] = (__bf16)(acc[r] + bb[nt]);
                *(bf16x4*)(buf + (nt * 16 + l16) * 72 + mt * 16 + quad * 4) = pk;
            }
        }
        #pragma unroll
        for (int kt = 0; kt < 2; ++kt)
            #pragma unroll
            for (int nf = 0; nf < 2; ++nf)
                vf[kt][nf] = *(const bf16x8*)(buf + (nf * 16 + l16) * 72 + kt * 32 + quad * 8);
    }
    __syncthreads();   // barrier 2: all xs reads done -> safe to overlay O staging

    // ---- attention per 16-row band: S -> softmax -> P (buf) -> P@V -> osw ----
    const float* rpeh = rpe + h * 4096;
    const float* mw   = mask + (size_t)(win % NWMASK) * 4096;
    #pragma unroll
    for (int mt = 0; mt < 4; ++mt) {
        f32x4 sc[4];
        #pragma unroll
        for (int nt = 0; nt < 4; ++nt) {
            f32x4 z = {0.f, 0.f, 0.f, 0.f};
            sc[nt] = __builtin_amdgcn_mfma_f32_16x16x32_bf16(qf[mt], kf[nt], z, 0, 0, 0);
        }
        float inv_s[4];
        #pragma unroll
        for (int r = 0; r < 4; ++r) {
            const int row = mt * 16 + quad * 4 + r;
            float mx = -3.0e38f;
            #pragma unroll
            for (int nt = 0; nt < 4; ++nt) {
                float lg = sc[nt][r] + rpeh[row * 64 + nt * 16 + l16] + mw[row * 64 + nt * 16 + l16];
                sc[nt][r] = lg;
                mx = fmaxf(mx, lg);
            }
            #pragma unroll
            for (int s = 1; s < 16; s <<= 1) mx = fmaxf(mx, __shfl_xor(mx, s, 64));
            float sum = 0.f;
            #pragma unroll
            for (int nt = 0; nt < 4; ++nt) {
                float e = __expf(sc[nt][r] - mx);
                sc[nt][r] = e;
                sum += e;
            }
            #pragma unroll
            for (int s = 1; s < 16; s <<= 1) sum += __shfl_xor(sum, s, 64);
            inv_s[r] = 1.0f / sum;
        }
        // P band (16x64) C-layout -> A-layout via wave-private buf
        #pragma unroll
        for (int nt = 0; nt < 4; ++nt)
            #pragma unroll
            for (int r = 0; r < 4; ++r)
                buf[(quad * 4 + r) * 72 + nt * 16 + l16] = (__bf16)sc[nt][r];
        f32x4 oa[2] = {{0.f,0.f,0.f,0.f},{0.f,0.f,0.f,0.f}};
        #pragma unroll
        for (int kt = 0; kt < 2; ++kt) {
            bf16x8 pf = *(const bf16x8*)(buf + l16 * 72 + kt * 32 + quad * 8);
            #pragma unroll
            for (int nf = 0; nf < 2; ++nf)
                oa[nf] = __builtin_amdgcn_mfma_f32_16x16x32_bf16(pf, vf[kt][nf], oa[nf], 0, 0, 0);
        }
        #pragma unroll
        for (int nf = 0; nf < 2; ++nf)
            #pragma unroll
            for (int r = 0; r < 4; ++r)
                osw[(mt * 16 + quad * 4 + r) * 34 + nf * 16 + l16] = (__bf16)(oa[nf][r] * inv_s[r]);
    }
    __syncthreads();   // barrier 3: O staging (all heads) ready

    // ---- proj GEMM: wave h = token band, K=128 over 4 heads' O ----
    bf16x8 of[4];
    #pragma unroll
    for (int kt = 0; kt < 4; ++kt)
        of[kt] = *(const bf16x8*)(smem + kt * 2176 + (h * 16 + l16) * 34 + quad * 8);
    #pragma unroll
    for (int nt = 0; nt < 8; ++nt) {
        const int ng = nt * 16 + l16;
        const float b = proj_b[ng];
        bf16x8 wf[4];
        #pragma unroll
        for (int kt = 0; kt < 4; ++kt)
            wf[kt] = *(const bf16x8*)(wproj + ng * 128 + kt * 32 + quad * 8);
        f32x4 acc = {0.f, 0.f, 0.f, 0.f};
        #pragma unroll
        for (int kt = 0; kt < 4; ++kt)
            acc = __builtin_amdgcn_mfma_f32_16x16x32_bf16(of[kt], wf[kt], acc, 0, 0, 0);
        float* dst = out + ((size_t)win * 64 + h * 16 + quad * 4) * 128 + ng;
        #pragma unroll
        for (int r = 0; r < 4; ++r) dst[(size_t)r * 128] = acc[r] + b;
    }
}

// ---------------- launch ----------------
extern "C" void kernel_launch(void* const* d_in, const int* in_sizes, int n_in,
                              void* d_out, int out_size, void* d_ws, size_t ws_size,
                              hipStream_t stream) {
    const float* x      = (const float*)d_in[0];
    const float* mask   = (const float*)d_in[1];
    const float* qkv_w  = (const float*)d_in[2];
    const float* qkv_b  = (const float*)d_in[3];
    const float* proj_w = (const float*)d_in[4];
    const float* proj_b = (const float*)d_in[5];
    const float* tbl    = (const float*)d_in[6];
    const int*   ridx   = (const int*)d_in[7];
    float* out = (float*)d_out;

    // ws: wqkv bf16 [384*128] | wproj bf16 [128*128] | rpe f32 [4*64*64]
    __bf16* wqkv  = (__bf16*)d_ws;
    __bf16* wproj = wqkv + 384 * 128;
    float*  rpe   = (float*)((char*)d_ws + 131072);

    prep<<<320, 256, 0, stream>>>(qkv_w, proj_w, tbl, ridx, wqkv, wproj, rpe);
    wattn_main<<<3136, 256, 0, stream>>>(x, mask, qkv_b, proj_b, wqkv, wproj, rpe, out);
}